// Round 1
// baseline (766.349 us; speedup 1.0000x reference)
//
#include <hip/hip_runtime.h>
#include <cstdint>
#include <cstddef>
#include <cmath>

#define N_TOK 2048
#define HDIM  2048
#define NEXP  16
#define IDIM  1024
#define SIDIM 2048
#define NTHREADS 256

typedef __attribute__((ext_vector_type(8))) short bf16x8;
typedef __attribute__((ext_vector_type(4))) float f32x4;

__device__ __forceinline__ uint32_t f2bf_u(float f) {
    union { float f; uint32_t u; } v; v.f = f;
    return (v.u + 0x7FFFu + ((v.u >> 16) & 1u)) >> 16;   // RNE
}

// 2x f32 -> packed bf16 (RNE), single instruction on gfx950.
__device__ __forceinline__ uint32_t cvtpk(float lo, float hi) {
    uint32_t r;
    asm("v_cvt_pk_bf16_f32 %0, %1, %2" : "=v"(r) : "v"(lo), "v"(hi));
    return r;
}

// XOR-swizzled 16B-chunk index for a tile with 64B rows (4 chunks/row).
// Conflict-free for both n-major b128 staging writes and MFMA-fragment
// b128 reads; keeps 16B alignment with zero padding.
__device__ __forceinline__ int swz(int row, int c) {
    return row * 4 + (c ^ ((row >> 1) & 3));
}

// ------------------------------------------------------------ x -> bf16 ----
__global__ __launch_bounds__(NTHREADS)
void convert_x_kernel(const float* __restrict__ x, unsigned short* __restrict__ xb)
{
    const size_t i = ((size_t)blockIdx.x * NTHREADS + threadIdx.x) * 8;
    float4 a = *(const float4*)(x + i);
    float4 b = *(const float4*)(x + i + 4);
    uint4 w = make_uint4(cvtpk(a.x, a.y), cvtpk(a.z, a.w),
                         cvtpk(b.x, b.y), cvtpk(b.z, b.w));
    *(uint4*)(xb + i) = w;
}

// ---------------------------------------------------------------- router ----
// fp32 throughout: top-2 selection must not be perturbed by bf16 rounding.
__global__ __launch_bounds__(NTHREADS)
void router_kernel(const float* __restrict__ x,
                   const float* __restrict__ rw,
                   float* __restrict__ logits_out,
                   int* __restrict__ cnt,
                   int* __restrict__ tok_list,
                   float* __restrict__ wt_list)
{
    const int n = blockIdx.x;
    const int tid = threadIdx.x;
    const float* xr = x + (size_t)n * HDIM;

    float acc[NEXP];
#pragma unroll
    for (int e = 0; e < NEXP; ++e) acc[e] = 0.f;

    for (int h = tid; h < HDIM; h += NTHREADS) {
        float xv = xr[h];
#pragma unroll
        for (int e = 0; e < NEXP; ++e) acc[e] += xv * rw[(size_t)e * HDIM + h];
    }

    __shared__ float red[NEXP][NTHREADS];
#pragma unroll
    for (int e = 0; e < NEXP; ++e) red[e][tid] = acc[e];
    __syncthreads();
    for (int s = NTHREADS / 2; s > 0; s >>= 1) {
        if (tid < s) {
#pragma unroll
            for (int e = 0; e < NEXP; ++e) red[e][tid] += red[e][tid + s];
        }
        __syncthreads();
    }

    if (tid < NEXP) logits_out[(size_t)n * NEXP + tid] = red[tid][0];

    if (tid == 0) {
        float l[NEXP];
#pragma unroll
        for (int e = 0; e < NEXP; ++e) l[e] = red[e][0];
        int e0 = 0;
#pragma unroll
        for (int e = 1; e < NEXP; ++e) if (l[e] > l[e0]) e0 = e;
        int e1 = (e0 == 0) ? 1 : 0;
#pragma unroll
        for (int e = 0; e < NEXP; ++e)
            if (e != e0 && l[e] > l[e1]) e1 = e;
        float t = expf(l[e1] - l[e0]);
        float s = 1.f + t;
        float rw0 = 1.f / s;
        float rw1 = t / s;
        int p0 = atomicAdd(&cnt[e0], 1);
        tok_list[e0 * N_TOK + p0] = n;
        wt_list[e0 * N_TOK + p0] = rw0;
        int p1 = atomicAdd(&cnt[e1], 1);
        tok_list[e1 * N_TOK + p1] = n;
        wt_list[e1 * N_TOK + p1] = rw1;
    }
}

__global__ void prefix_kernel(const int* __restrict__ cnt, int* __restrict__ base)
{
    if (threadIdx.x == 0) {
        int s = 0;
        for (int e = 0; e < NEXP; ++e) { base[e] = s; s += cnt[e]; }
    }
}

// -------------------------------------- MFMA dual GEMM + SwiGLU (bf16 out) --
// Y[yb+m][n] = bf16( silu(X@Wg) * (X@Wu) ).  Tile: 128m x 64n x 32k.
// 4 waves 2x2; wave tile 64m x 32n per matrix.
// 2-phase pipeline: double-buffered LDS, ONE raw s_barrier per 32-k tile,
// no vmcnt drain at the barrier (raw s_barrier + counted compiler waits)
// so the next tile's 18 global loads stay in flight across it.
__global__ __launch_bounds__(NTHREADS)
void dual_swiglu_mfma(const unsigned short* __restrict__ Xb,  // bf16 [N_TOK][HDIM]
                      const float* __restrict__ WgAll,
                      const float* __restrict__ WuAll,
                      unsigned short* __restrict__ Y,         // bf16 [rows][Icols]
                      const int* __restrict__ cnt,
                      const int* __restrict__ base,
                      const int* __restrict__ tok_list,
                      const int Icols)
{
    const int e  = blockIdx.z;
    const int m0 = blockIdx.y * 128;
    const int n0 = blockIdx.x * 64;
    const bool gathered = (tok_list != nullptr);
    const int M = gathered ? cnt[e] : N_TOK;
    if (m0 >= M) return;
    const float* Wg = WgAll + (size_t)e * HDIM * Icols;
    const float* Wu = WuAll + (size_t)e * HDIM * Icols;
    const int yb = gathered ? base[e] : 0;

    __shared__ short As[2][128 * 32];   // [m][k] swizzled, double-buffered
    __shared__ short Gs[2][64 * 32];    // [n][k] swizzled (transposed W)
    __shared__ short Us[2][64 * 32];

    const int tid  = threadIdx.x;
    const int lane = tid & 63;
    const int wave = tid >> 6;
    const int wm   = wave >> 1;
    const int wn   = wave & 1;
    const int l15  = lane & 15;
    const int q    = lane >> 4;

    // A staging: thread -> (row=tid>>1, chunk pair at*2, at*2+1)
    const int ar = tid >> 1;
    const int at = tid & 1;
    const int slotA = m0 + ar;
    int xrow;
    if (gathered) xrow = tok_list[e * N_TOK + ((slotA < M) ? slotA : (M - 1))];
    else          xrow = slotA;
    const unsigned short* xp = Xb + (size_t)xrow * HDIM + at * 16;

    // W staging: thread -> column n = tid&63, k-chunk c = tid>>6 (8 k each).
    // Column loads: lanes read consecutive n -> coalesced 256B per instr.
    const int wcn = tid & 63;
    const int wcc = tid >> 6;
    const float* gp = Wg + n0 + wcn;
    const float* up = Wu + n0 + wcn;

    f32x4 accg[4][2], accu[4][2];
#pragma unroll
    for (int i = 0; i < 4; ++i)
#pragma unroll
        for (int j = 0; j < 2; ++j) {
            accg[i][j] = (f32x4){0.f, 0.f, 0.f, 0.f};
            accu[i][j] = (f32x4){0.f, 0.f, 0.f, 0.f};
        }

    struct RegTile { uint4 x0, x1; float g[8], u[8]; };
    RegTile r0, r1;

    auto ldtile = [&](RegTile& r, int kk) {
        r.x0 = *(const uint4*)(xp + kk);
        r.x1 = *(const uint4*)(xp + kk + 8);
        const float* gk = gp + (size_t)(kk + wcc * 8) * Icols;
        const float* uk = up + (size_t)(kk + wcc * 8) * Icols;
#pragma unroll
        for (int j = 0; j < 8; ++j) {
            r.g[j] = gk[(size_t)j * Icols];
            r.u[j] = uk[(size_t)j * Icols];
        }
    };
    auto sttile = [&](const RegTile& r, short* As_, short* Gs_, short* Us_) {
        *(uint4*)(As_ + swz(ar, at * 2 + 0) * 8) = r.x0;
        *(uint4*)(As_ + swz(ar, at * 2 + 1) * 8) = r.x1;
        uint4 gw = make_uint4(cvtpk(r.g[0], r.g[1]), cvtpk(r.g[2], r.g[3]),
                              cvtpk(r.g[4], r.g[5]), cvtpk(r.g[6], r.g[7]));
        uint4 uw = make_uint4(cvtpk(r.u[0], r.u[1]), cvtpk(r.u[2], r.u[3]),
                              cvtpk(r.u[4], r.u[5]), cvtpk(r.u[6], r.u[7]));
        *(uint4*)(Gs_ + swz(wcn, wcc) * 8) = gw;
        *(uint4*)(Us_ + swz(wcn, wcc) * 8) = uw;
    };
    auto mmstep = [&](const short* As_, const short* Gs_, const short* Us_) {
        bf16x8 af[4], bg[2], bu[2];
#pragma unroll
        for (int i = 0; i < 4; ++i)
            af[i] = *(const bf16x8*)(As_ + swz(wm * 64 + i * 16 + l15, q) * 8);
#pragma unroll
        for (int j = 0; j < 2; ++j) {
            bg[j] = *(const bf16x8*)(Gs_ + swz(wn * 32 + j * 16 + l15, q) * 8);
            bu[j] = *(const bf16x8*)(Us_ + swz(wn * 32 + j * 16 + l15, q) * 8);
        }
#pragma unroll
        for (int i = 0; i < 4; ++i)
#pragma unroll
            for (int j = 0; j < 2; ++j) {
                accg[i][j] = __builtin_amdgcn_mfma_f32_16x16x32_bf16(af[i], bg[j], accg[i][j], 0, 0, 0);
                accu[i][j] = __builtin_amdgcn_mfma_f32_16x16x32_bf16(af[i], bu[j], accu[i][j], 0, 0, 0);
            }
    };

    ldtile(r0, 0);
    for (int k0 = 0; k0 < HDIM; k0 += 64) {
        const int k1 = k0 + 32;
        int k2 = k0 + 64; if (k2 >= HDIM) k2 = 0;   // tail prefetch: valid addr, discarded

        ldtile(r1, k1);                      // issue-early: overlaps everything below
        sttile(r0, As[0], Gs[0], Us[0]);     // compiler waits vmcnt for r0 only
        asm volatile("s_waitcnt lgkmcnt(0)" ::: "memory");
        __builtin_amdgcn_s_barrier();
        __builtin_amdgcn_sched_barrier(0);
        mmstep(As[0], Gs[0], Us[0]);

        ldtile(r0, k2);
        sttile(r1, As[1], Gs[1], Us[1]);
        asm volatile("s_waitcnt lgkmcnt(0)" ::: "memory");
        __builtin_amdgcn_s_barrier();
        __builtin_amdgcn_sched_barrier(0);
        mmstep(As[1], Gs[1], Us[1]);
    }

    // epilogue: silu(g)*u -> bf16
#pragma unroll
    for (int i = 0; i < 4; ++i) {
#pragma unroll
        for (int r = 0; r < 4; ++r) {
            const int slot = m0 + wm * 64 + i * 16 + q * 4 + r;
            if (slot < M) {
                unsigned short* yrow = Y + (size_t)(yb + slot) * Icols;
#pragma unroll
                for (int j = 0; j < 2; ++j) {
                    const int col = n0 + wn * 32 + j * 16 + l15;
                    float g = accg[i][j][r];
                    float u = accu[i][j][r];
                    float y = (g / (1.f + expf(-g))) * u;
                    yrow[col] = (unsigned short)f2bf_u(y);
                }
            }
        }
    }
}

// -------------------------------- MFMA down GEMM (bf16 A, fp32 W, fp32 out) --
// plain  (tok_list==null): out[m][n]  = A[m] @ W        (overwrites)
// scatter(tok_list!=null): out[tok[m]][n] += wt[m] * (A[yb+m] @ W[e])
// Tile: 64m x 128n x 32k; 4 waves 2x2; wave tile 32x64.
// Same 2-phase non-draining pipeline as dual_swiglu_mfma.
__global__ __launch_bounds__(NTHREADS)
void down_mfma(const unsigned short* __restrict__ A,  // bf16 [rows][K]
               const float* __restrict__ WdAll,       // [E?][K][HDIM]
               float* __restrict__ out,
               const int* __restrict__ cnt,
               const int* __restrict__ base,
               const int* __restrict__ tok_list,
               const float* __restrict__ wt_list,
               const int K)
{
    const int e  = blockIdx.z;
    const int m0 = blockIdx.y * 64;
    const int n0 = blockIdx.x * 128;
    const bool scatter = (tok_list != nullptr);
    const int M = scatter ? cnt[e] : N_TOK;
    if (m0 >= M) return;
    const float* Wd = WdAll + (size_t)e * K * HDIM;
    const int yb = scatter ? base[e] : 0;

    __shared__ short As[2][64 * 32];    // [m][k] swizzled, double-buffered
    __shared__ short Bs[2][128 * 32];   // [n][k] swizzled (transposed W)

    const int tid  = threadIdx.x;
    const int lane = tid & 63;
    const int wave = tid >> 6;
    const int wm   = wave >> 1;
    const int wn   = wave & 1;
    const int l15  = lane & 15;
    const int q    = lane >> 4;

    // A staging: thread -> (row=tid>>2, chunk tid&3), one uint4
    const int ar = tid >> 2;
    const int ac = tid & 3;
    const int slotA = m0 + ar;
    const int arow = yb + ((slotA < M) ? slotA : (M - 1));
    const unsigned short* ap = A + (size_t)arow * K + ac * 8;

    // B staging: thread -> column n = tid&127, chunk pair {2h, 2h+1}, h=tid>>7
    const int bn = tid & 127;
    const int bh = tid >> 7;
    const float* bp = Wd + n0 + bn;

    f32x4 acc[2][4];
#pragma unroll
    for (int i = 0; i < 2; ++i)
#pragma unroll
        for (int j = 0; j < 4; ++j) acc[i][j] = (f32x4){0.f, 0.f, 0.f, 0.f};

    struct RegTileD { uint4 x; float b[16]; };
    RegTileD r0, r1;

    auto ldtile = [&](RegTileD& r, int kk) {
        r.x = *(const uint4*)(ap + kk);
        const float* bk = bp + (size_t)(kk + bh * 16) * HDIM;
#pragma unroll
        for (int c = 0; c < 2; ++c)
#pragma unroll
            for (int j = 0; j < 8; ++j)
                r.b[c * 8 + j] = bk[(size_t)(c * 8 + j) * HDIM];
    };
    auto sttile = [&](const RegTileD& r, short* As_, short* Bs_) {
        *(uint4*)(As_ + swz(ar, ac) * 8) = r.x;
        uint4 w0 = make_uint4(cvtpk(r.b[0], r.b[1]),  cvtpk(r.b[2], r.b[3]),
                              cvtpk(r.b[4], r.b[5]),  cvtpk(r.b[6], r.b[7]));
        uint4 w1 = make_uint4(cvtpk(r.b[8], r.b[9]),  cvtpk(r.b[10], r.b[11]),
                              cvtpk(r.b[12], r.b[13]), cvtpk(r.b[14], r.b[15]));
        *(uint4*)(Bs_ + swz(bn, bh * 2 + 0) * 8) = w0;
        *(uint4*)(Bs_ + swz(bn, bh * 2 + 1) * 8) = w1;
    };
    auto mmstep = [&](const short* As_, const short* Bs_) {
        bf16x8 af[2], bfr[4];
#pragma unroll
        for (int i = 0; i < 2; ++i)
            af[i] = *(const bf16x8*)(As_ + swz(wm * 32 + i * 16 + l15, q) * 8);
#pragma unroll
        for (int j = 0; j < 4; ++j)
            bfr[j] = *(const bf16x8*)(Bs_ + swz(wn * 64 + j * 16 + l15, q) * 8);
#pragma unroll
        for (int i = 0; i < 2; ++i)
#pragma unroll
            for (int j = 0; j < 4; ++j)
                acc[i][j] = __builtin_amdgcn_mfma_f32_16x16x32_bf16(af[i], bfr[j], acc[i][j], 0, 0, 0);
    };

    ldtile(r0, 0);
    for (int k0 = 0; k0 < K; k0 += 64) {
        const int k1 = k0 + 32;
        int k2 = k0 + 64; if (k2 >= K) k2 = 0;      // tail prefetch: valid addr, discarded

        ldtile(r1, k1);
        sttile(r0, As[0], Bs[0]);
        asm volatile("s_waitcnt lgkmcnt(0)" ::: "memory");
        __builtin_amdgcn_s_barrier();
        __builtin_amdgcn_sched_barrier(0);
        mmstep(As[0], Bs[0]);

        ldtile(r0, k2);
        sttile(r1, As[1], Bs[1]);
        asm volatile("s_waitcnt lgkmcnt(0)" ::: "memory");
        __builtin_amdgcn_s_barrier();
        __builtin_amdgcn_sched_barrier(0);
        mmstep(As[1], Bs[1]);
    }

#pragma unroll
    for (int i = 0; i < 2; ++i) {
#pragma unroll
        for (int r = 0; r < 4; ++r) {
            const int slot = m0 + wm * 32 + i * 16 + q * 4 + r;
            if (slot >= M) continue;
            if (scatter) {
                const int tok = tok_list[e * N_TOK + slot];
                const float wt = wt_list[e * N_TOK + slot];
                float* orow = out + (size_t)tok * HDIM;
#pragma unroll
                for (int j = 0; j < 4; ++j) {
                    const int col = n0 + wn * 64 + j * 16 + l15;
                    atomicAdd(&orow[col], wt * acc[i][j][r]);
                }
            } else {
                float* orow = out + (size_t)slot * HDIM;
#pragma unroll
                for (int j = 0; j < 4; ++j) {
                    const int col = n0 + wn * 64 + j * 16 + l15;
                    orow[col] = acc[i][j][r];
                }
            }
        }
    }
}

// ------------------------------------------------------------------ launch --
extern "C" void kernel_launch(void* const* d_in, const int* in_sizes, int n_in,
                              void* d_out, int out_size, void* d_ws, size_t ws_size,
                              hipStream_t stream)
{
    const float* x       = (const float*)d_in[0];
    const float* rw      = (const float*)d_in[1];
    const float* w_gate  = (const float*)d_in[2];
    const float* w_up    = (const float*)d_in[3];
    const float* w_down  = (const float*)d_in[4];
    const float* ws_gate = (const float*)d_in[5];
    const float* ws_up   = (const float*)d_in[6];
    const float* ws_down = (const float*)d_in[7];

    float* out    = (float*)d_out;                       // [N_TOK, HDIM]
    float* logits = out + (size_t)N_TOK * HDIM;          // [N_TOK, NEXP]

    // workspace (~25 MB)
    char* w = (char*)d_ws;
    int* cnt      = (int*)w;                             // 16
    int* base     = cnt + 16;                            // 16
    int* tok_list = base + 16;                           // E*N
    float* wt_list = (float*)(tok_list + NEXP * N_TOK);  // E*N
    uintptr_t p = (uintptr_t)(wt_list + NEXP * N_TOK);
    p = (p + 255) & ~(uintptr_t)255;
    unsigned short* Xb       = (unsigned short*)p;                 // bf16 [N_TOK][HDIM]
    unsigned short* A_shared = Xb + (size_t)N_TOK * HDIM;          // bf16 [N_TOK][SIDIM]
    unsigned short* Ybuf     = A_shared + (size_t)N_TOK * SIDIM;   // bf16 [N_TOK*2][IDIM]

    hipMemsetAsync(cnt, 0, 16 * sizeof(int), stream);

    convert_x_kernel<<<dim3((N_TOK * HDIM) / (NTHREADS * 8)), dim3(NTHREADS), 0, stream>>>(x, Xb);
    router_kernel<<<dim3(N_TOK), dim3(NTHREADS), 0, stream>>>(
        x, rw, logits, cnt, tok_list, wt_list);
    prefix_kernel<<<dim3(1), dim3(64), 0, stream>>>(cnt, base);

    // shared expert
    dual_swiglu_mfma<<<dim3(SIDIM / 64, N_TOK / 128, 1), dim3(NTHREADS), 0, stream>>>(
        Xb, ws_gate, ws_up, A_shared, cnt, base, nullptr, SIDIM);
    down_mfma<<<dim3(HDIM / 128, N_TOK / 64, 1), dim3(NTHREADS), 0, stream>>>(
        A_shared, ws_down, out, cnt, base, nullptr, nullptr, SIDIM);

    // sparse experts (stream-ordered after the shared write of `out`)
    dual_swiglu_mfma<<<dim3(IDIM / 64, N_TOK / 128, NEXP), dim3(NTHREADS), 0, stream>>>(
        Xb, w_gate, w_up, Ybuf, cnt, base, tok_list, IDIM);
    down_mfma<<<dim3(HDIM / 128, N_TOK / 64, NEXP), dim3(NTHREADS), 0, stream>>>(
        Ybuf, w_down, out, cnt, base, tok_list, wt_list, IDIM);
}

// Round 2
// 756.398 us; speedup vs baseline: 1.0132x; 1.0132x over previous
//
#include <hip/hip_runtime.h>
#include <cstdint>
#include <cstddef>
#include <cmath>

#define N_TOK 2048
#define HDIM  2048
#define NEXP  16
#define IDIM  1024
#define SIDIM 2048
#define NTHREADS 256

typedef __attribute__((ext_vector_type(8))) short bf16x8;
typedef __attribute__((ext_vector_type(4))) float f32x4;

__device__ __forceinline__ uint32_t f2bf_u(float f) {
    union { float f; uint32_t u; } v; v.f = f;
    return (v.u + 0x7FFFu + ((v.u >> 16) & 1u)) >> 16;   // RNE
}

// 2x f32 -> packed bf16 (RNE), single instruction on gfx950.
__device__ __forceinline__ uint32_t cvtpk(float lo, float hi) {
    uint32_t r;
    asm("v_cvt_pk_bf16_f32 %0, %1, %2" : "=v"(r) : "v"(lo), "v"(hi));
    return r;
}

// XOR-swizzled 16B-chunk index for a tile with 64B rows (4 chunks/row).
// Conflict-free (8-access/bank floor) for both n-major b128 staging writes
// and MFMA-fragment b128 reads; keeps 16B alignment with zero padding.
__device__ __forceinline__ int swz(int row, int c) {
    return row * 4 + (c ^ ((row >> 1) & 3));
}

// ------------------------------------------------------------ x -> bf16 ----
__global__ __launch_bounds__(NTHREADS)
void convert_x_kernel(const float* __restrict__ x, unsigned short* __restrict__ xb)
{
    const size_t i = ((size_t)blockIdx.x * NTHREADS + threadIdx.x) * 8;
    float4 a = *(const float4*)(x + i);
    float4 b = *(const float4*)(x + i + 4);
    uint4 w = make_uint4(cvtpk(a.x, a.y), cvtpk(a.z, a.w),
                         cvtpk(b.x, b.y), cvtpk(b.z, b.w));
    *(uint4*)(xb + i) = w;
}

// ---------------------------------------------------------------- router ----
// fp32 throughout: top-2 selection must not be perturbed by bf16 rounding.
__global__ __launch_bounds__(NTHREADS)
void router_kernel(const float* __restrict__ x,
                   const float* __restrict__ rw,
                   float* __restrict__ logits_out,
                   int* __restrict__ cnt,
                   int* __restrict__ tok_list,
                   float* __restrict__ wt_list)
{
    const int n = blockIdx.x;
    const int tid = threadIdx.x;
    const float* xr = x + (size_t)n * HDIM;

    float acc[NEXP];
#pragma unroll
    for (int e = 0; e < NEXP; ++e) acc[e] = 0.f;

    for (int h = tid; h < HDIM; h += NTHREADS) {
        float xv = xr[h];
#pragma unroll
        for (int e = 0; e < NEXP; ++e) acc[e] += xv * rw[(size_t)e * HDIM + h];
    }

    __shared__ float red[NEXP][NTHREADS];
#pragma unroll
    for (int e = 0; e < NEXP; ++e) red[e][tid] = acc[e];
    __syncthreads();
    for (int s = NTHREADS / 2; s > 0; s >>= 1) {
        if (tid < s) {
#pragma unroll
            for (int e = 0; e < NEXP; ++e) red[e][tid] += red[e][tid + s];
        }
        __syncthreads();
    }

    if (tid < NEXP) logits_out[(size_t)n * NEXP + tid] = red[tid][0];

    if (tid == 0) {
        float l[NEXP];
#pragma unroll
        for (int e = 0; e < NEXP; ++e) l[e] = red[e][0];
        int e0 = 0;
#pragma unroll
        for (int e = 1; e < NEXP; ++e) if (l[e] > l[e0]) e0 = e;
        int e1 = (e0 == 0) ? 1 : 0;
#pragma unroll
        for (int e = 0; e < NEXP; ++e)
            if (e != e0 && l[e] > l[e1]) e1 = e;
        float t = expf(l[e1] - l[e0]);
        float s = 1.f + t;
        float rw0 = 1.f / s;
        float rw1 = t / s;
        int p0 = atomicAdd(&cnt[e0], 1);
        tok_list[e0 * N_TOK + p0] = n;
        wt_list[e0 * N_TOK + p0] = rw0;
        int p1 = atomicAdd(&cnt[e1], 1);
        tok_list[e1 * N_TOK + p1] = n;
        wt_list[e1 * N_TOK + p1] = rw1;
    }
}

__global__ void prefix_kernel(const int* __restrict__ cnt, int* __restrict__ base)
{
    if (threadIdx.x == 0) {
        int s = 0;
        for (int e = 0; e < NEXP; ++e) { base[e] = s; s += cnt[e]; }
    }
}

// -------------------------------------- MFMA dual GEMM + SwiGLU (bf16 out) --
// Merged shared+sparse dispatch:
//   z == 0  : shared expert  (Wg=Wsg, Icols=SIDIM, all tokens, Y=Yshared)
//   z >= 1  : sparse expert e=z-1 (Icols=IDIM, gathered rows, Y=Ysparse)
// Y[yb+m][n] = bf16( silu(X@Wg) * (X@Wu) ).  Tile: 128m x 64n x 32k.
// 4 waves 2x2; wave tile 64m x 32n per matrix. Register-prefetch pipeline
// (single-buffered LDS: proven no-spill structure).
__global__ __launch_bounds__(NTHREADS)
void dual_swiglu_mfma(const unsigned short* __restrict__ Xb,  // bf16 [N_TOK][HDIM]
                      const float* __restrict__ WgAll,        // sparse [E][H][I]
                      const float* __restrict__ WuAll,
                      const float* __restrict__ Wsg,          // shared [H][SI]
                      const float* __restrict__ Wsu,
                      unsigned short* __restrict__ Ysparse,   // bf16 [2*N_TOK][IDIM]
                      unsigned short* __restrict__ Yshared,   // bf16 [N_TOK][SIDIM]
                      const int* __restrict__ cnt,
                      const int* __restrict__ base,
                      const int* __restrict__ tok_list)
{
    const int z  = blockIdx.z;
    const bool shared_path = (z == 0);
    const int e  = z - 1;
    const int Icols = shared_path ? SIDIM : IDIM;
    const int m0 = blockIdx.y * 128;
    const int n0 = blockIdx.x * 64;
    if (n0 >= Icols) return;
    const int M = shared_path ? N_TOK : cnt[e];
    if (m0 >= M) return;
    const float* Wg = shared_path ? Wsg : WgAll + (size_t)e * HDIM * IDIM;
    const float* Wu = shared_path ? Wsu : WuAll + (size_t)e * HDIM * IDIM;
    unsigned short* Y = shared_path ? Yshared : Ysparse;
    const int yb = shared_path ? 0 : base[e];

    __shared__ short As[128 * 32];   // [m][k] swizzled
    __shared__ short Gs[64 * 32];    // [n][k] swizzled (transposed W)
    __shared__ short Us[64 * 32];

    const int tid  = threadIdx.x;
    const int lane = tid & 63;
    const int wave = tid >> 6;
    const int wm   = wave >> 1;
    const int wn   = wave & 1;
    const int l15  = lane & 15;
    const int q    = lane >> 4;

    // A staging: thread -> (row=tid>>1, chunk pair at*2, at*2+1)
    const int ar = tid >> 1;
    const int at = tid & 1;
    const int slotA = m0 + ar;
    int xrow;
    if (!shared_path) xrow = tok_list[e * N_TOK + ((slotA < M) ? slotA : (M - 1))];
    else              xrow = slotA;
    const unsigned short* xp = Xb + (size_t)xrow * HDIM + at * 16;

    // W staging: thread -> column n = tid&63, k-chunk c = tid>>6 (8 k each).
    // Column loads: lanes read consecutive n -> coalesced 256B per instr.
    const int wcn = tid & 63;
    const int wcc = tid >> 6;
    const float* gp = Wg + n0 + wcn;
    const float* up = Wu + n0 + wcn;

    f32x4 accg[4][2], accu[4][2];
#pragma unroll
    for (int i = 0; i < 4; ++i)
#pragma unroll
        for (int j = 0; j < 2; ++j) {
            accg[i][j] = (f32x4){0.f, 0.f, 0.f, 0.f};
            accu[i][j] = (f32x4){0.f, 0.f, 0.f, 0.f};
        }

    uint4 a0, a1;
    float g8[8], u8[8];
    auto ldtile = [&](int kk) {
        a0 = *(const uint4*)(xp + kk);
        a1 = *(const uint4*)(xp + kk + 8);
#pragma unroll
        for (int j = 0; j < 8; ++j) {
            g8[j] = gp[(size_t)(kk + wcc * 8 + j) * Icols];
            u8[j] = up[(size_t)(kk + wcc * 8 + j) * Icols];
        }
    };

    ldtile(0);
    for (int k0 = 0; k0 < HDIM; k0 += 32) {
        __syncthreads();
        *(uint4*)(As + swz(ar, at * 2 + 0) * 8) = a0;
        *(uint4*)(As + swz(ar, at * 2 + 1) * 8) = a1;
        uint4 gw = make_uint4(cvtpk(g8[0], g8[1]), cvtpk(g8[2], g8[3]),
                              cvtpk(g8[4], g8[5]), cvtpk(g8[6], g8[7]));
        uint4 uw = make_uint4(cvtpk(u8[0], u8[1]), cvtpk(u8[2], u8[3]),
                              cvtpk(u8[4], u8[5]), cvtpk(u8[6], u8[7]));
        *(uint4*)(Gs + swz(wcn, wcc) * 8) = gw;
        *(uint4*)(Us + swz(wcn, wcc) * 8) = uw;
        __syncthreads();

        int kn = k0 + 32;
        if (kn >= HDIM) kn = k0;     // redundant last load, keeps loop uniform
        ldtile(kn);                  // overlaps with MFMA below

        bf16x8 af[4], bg[2], bu[2];
#pragma unroll
        for (int i = 0; i < 4; ++i)
            af[i] = *(const bf16x8*)(As + swz(wm * 64 + i * 16 + l15, q) * 8);
#pragma unroll
        for (int j = 0; j < 2; ++j) {
            bg[j] = *(const bf16x8*)(Gs + swz(wn * 32 + j * 16 + l15, q) * 8);
            bu[j] = *(const bf16x8*)(Us + swz(wn * 32 + j * 16 + l15, q) * 8);
        }
#pragma unroll
        for (int i = 0; i < 4; ++i)
#pragma unroll
            for (int j = 0; j < 2; ++j) {
                accg[i][j] = __builtin_amdgcn_mfma_f32_16x16x32_bf16(af[i], bg[j], accg[i][j], 0, 0, 0);
                accu[i][j] = __builtin_amdgcn_mfma_f32_16x16x32_bf16(af[i], bu[j], accu[i][j], 0, 0, 0);
            }
    }

    // epilogue: silu(g)*u -> bf16
#pragma unroll
    for (int i = 0; i < 4; ++i) {
#pragma unroll
        for (int r = 0; r < 4; ++r) {
            const int slot = m0 + wm * 64 + i * 16 + q * 4 + r;
            if (slot < M) {
                unsigned short* yrow = Y + (size_t)(yb + slot) * Icols;
#pragma unroll
                for (int j = 0; j < 2; ++j) {
                    const int col = n0 + wn * 32 + j * 16 + l15;
                    float g = accg[i][j][r];
                    float u = accu[i][j][r];
                    float y = (g / (1.f + expf(-g))) * u;
                    yrow[col] = (unsigned short)f2bf_u(y);
                }
            }
        }
    }
}

// -------------------------------- MFMA down GEMM (bf16 A, fp32 W, fp32 out) --
// Merged shared+sparse dispatch, both paths atomicAdd into pre-zeroed out:
//   z == 0 : out[m][n]      += A_shared[m] @ Wsd        (K=SIDIM, wt=1)
//   z >= 1 : out[tok[m]][n] += wt[m] * (Ysp[yb+m] @ Wd[e])  (K=IDIM)
// Tile: 64m x 128n x 32k; 4 waves 2x2; wave tile 32x64. Prefetch pipeline.
__global__ __launch_bounds__(NTHREADS)
void down_mfma(const unsigned short* __restrict__ Ash,   // bf16 [N_TOK][SIDIM]
               const unsigned short* __restrict__ Asp,   // bf16 [2*N_TOK][IDIM]
               const float* __restrict__ Wsd,            // [SIDIM][HDIM]
               const float* __restrict__ WdAll,          // [E][IDIM][HDIM]
               float* __restrict__ out,
               const int* __restrict__ cnt,
               const int* __restrict__ base,
               const int* __restrict__ tok_list,
               const float* __restrict__ wt_list)
{
    const int z  = blockIdx.z;
    const bool shared_path = (z == 0);
    const int e  = z - 1;
    const int K  = shared_path ? SIDIM : IDIM;
    const int m0 = blockIdx.y * 64;
    const int n0 = blockIdx.x * 128;
    const int M = shared_path ? N_TOK : cnt[e];
    if (m0 >= M) return;
    const unsigned short* A = shared_path ? Ash : Asp;
    const float* Wd = shared_path ? Wsd : WdAll + (size_t)e * IDIM * HDIM;
    const int yb = shared_path ? 0 : base[e];

    __shared__ short As[64 * 32];    // [m][k] swizzled
    __shared__ short Bs[128 * 32];   // [n][k] swizzled (transposed W)

    const int tid  = threadIdx.x;
    const int lane = tid & 63;
    const int wave = tid >> 6;
    const int wm   = wave >> 1;
    const int wn   = wave & 1;
    const int l15  = lane & 15;
    const int q    = lane >> 4;

    // A staging: thread -> (row=tid>>2, chunk tid&3), one uint4
    const int ar = tid >> 2;
    const int ac = tid & 3;
    const int slotA = m0 + ar;
    const int arow = yb + ((slotA < M) ? slotA : (M - 1));
    const unsigned short* ap = A + (size_t)arow * K + ac * 8;

    // B staging: thread -> column n = tid&127, chunk pair {2h, 2h+1}, h=tid>>7
    const int bn = tid & 127;
    const int bh = tid >> 7;
    const float* bp = Wd + n0 + bn;

    f32x4 acc[2][4];
#pragma unroll
    for (int i = 0; i < 2; ++i)
#pragma unroll
        for (int j = 0; j < 4; ++j) acc[i][j] = (f32x4){0.f, 0.f, 0.f, 0.f};

    uint4 a0;
    float b16[16];
    auto ldtile = [&](int kk) {
        a0 = *(const uint4*)(ap + kk);
#pragma unroll
        for (int c = 0; c < 2; ++c)
#pragma unroll
            for (int j = 0; j < 8; ++j)
                b16[c * 8 + j] = bp[(size_t)(kk + (bh * 2 + c) * 8 + j) * HDIM];
    };

    ldtile(0);
    for (int k0 = 0; k0 < K; k0 += 32) {
        __syncthreads();
        *(uint4*)(As + swz(ar, ac) * 8) = a0;
        uint4 w0 = make_uint4(cvtpk(b16[0], b16[1]),  cvtpk(b16[2], b16[3]),
                              cvtpk(b16[4], b16[5]),  cvtpk(b16[6], b16[7]));
        uint4 w1 = make_uint4(cvtpk(b16[8], b16[9]),  cvtpk(b16[10], b16[11]),
                              cvtpk(b16[12], b16[13]), cvtpk(b16[14], b16[15]));
        *(uint4*)(Bs + swz(bn, bh * 2 + 0) * 8) = w0;
        *(uint4*)(Bs + swz(bn, bh * 2 + 1) * 8) = w1;
        __syncthreads();

        int kn = k0 + 32;
        if (kn >= K) kn = k0;
        ldtile(kn);

        bf16x8 af[2], bfr[4];
#pragma unroll
        for (int i = 0; i < 2; ++i)
            af[i] = *(const bf16x8*)(As + swz(wm * 32 + i * 16 + l15, q) * 8);
#pragma unroll
        for (int j = 0; j < 4; ++j)
            bfr[j] = *(const bf16x8*)(Bs + swz(wn * 64 + j * 16 + l15, q) * 8);
#pragma unroll
        for (int i = 0; i < 2; ++i)
#pragma unroll
            for (int j = 0; j < 4; ++j)
                acc[i][j] = __builtin_amdgcn_mfma_f32_16x16x32_bf16(af[i], bfr[j], acc[i][j], 0, 0, 0);
    }

#pragma unroll
    for (int i = 0; i < 2; ++i) {
#pragma unroll
        for (int r = 0; r < 4; ++r) {
            const int slot = m0 + wm * 32 + i * 16 + q * 4 + r;
            if (slot >= M) continue;
            const int tok  = shared_path ? slot : tok_list[e * N_TOK + slot];
            const float wt = shared_path ? 1.f  : wt_list[e * N_TOK + slot];
            float* orow = out + (size_t)tok * HDIM;
#pragma unroll
            for (int j = 0; j < 4; ++j) {
                const int col = n0 + wn * 64 + j * 16 + l15;
                atomicAdd(&orow[col], wt * acc[i][j][r]);
            }
        }
    }
}

// ------------------------------------------------------------------ launch --
extern "C" void kernel_launch(void* const* d_in, const int* in_sizes, int n_in,
                              void* d_out, int out_size, void* d_ws, size_t ws_size,
                              hipStream_t stream)
{
    const float* x       = (const float*)d_in[0];
    const float* rw      = (const float*)d_in[1];
    const float* w_gate  = (const float*)d_in[2];
    const float* w_up    = (const float*)d_in[3];
    const float* w_down  = (const float*)d_in[4];
    const float* ws_gate = (const float*)d_in[5];
    const float* ws_up   = (const float*)d_in[6];
    const float* ws_down = (const float*)d_in[7];

    float* out    = (float*)d_out;                       // [N_TOK, HDIM]
    float* logits = out + (size_t)N_TOK * HDIM;          // [N_TOK, NEXP]

    // workspace (~25 MB)
    char* w = (char*)d_ws;
    int* cnt      = (int*)w;                             // 16
    int* base     = cnt + 16;                            // 16
    int* tok_list = base + 16;                           // E*N
    float* wt_list = (float*)(tok_list + NEXP * N_TOK);  // E*N
    uintptr_t p = (uintptr_t)(wt_list + NEXP * N_TOK);
    p = (p + 255) & ~(uintptr_t)255;
    unsigned short* Xb       = (unsigned short*)p;                 // bf16 [N_TOK][HDIM]
    unsigned short* A_shared = Xb + (size_t)N_TOK * HDIM;          // bf16 [N_TOK][SIDIM]
    unsigned short* Ybuf     = A_shared + (size_t)N_TOK * SIDIM;   // bf16 [N_TOK*2][IDIM]

    hipMemsetAsync(cnt, 0, 16 * sizeof(int), stream);
    hipMemsetAsync(out, 0, (size_t)N_TOK * HDIM * sizeof(float), stream);

    convert_x_kernel<<<dim3((N_TOK * HDIM) / (NTHREADS * 8)), dim3(NTHREADS), 0, stream>>>(x, Xb);
    router_kernel<<<dim3(N_TOK), dim3(NTHREADS), 0, stream>>>(
        x, rw, logits, cnt, tok_list, wt_list);
    prefix_kernel<<<dim3(1), dim3(64), 0, stream>>>(cnt, base);

    // merged dual SwiGLU: z=0 shared expert, z in [1,16] sparse experts.
    dual_swiglu_mfma<<<dim3(SIDIM / 64, N_TOK / 128, NEXP + 1), dim3(NTHREADS), 0, stream>>>(
        Xb, w_gate, w_up, ws_gate, ws_up, Ybuf, A_shared, cnt, base, tok_list);

    // merged down GEMM: both paths accumulate into pre-zeroed out.
    down_mfma<<<dim3(HDIM / 128, N_TOK / 64, NEXP + 1), dim3(NTHREADS), 0, stream>>>(
        A_shared, Ybuf, ws_down, w_down, out, cnt, base, tok_list, wt_list);
}